// Round 3
// baseline (925.786 us; speedup 1.0000x reference)
//
#include <hip/hip_runtime.h>

#define BATCH 16
#define LSEQ  2048
#define DDIM  128
#define EPSV  1e-12f
#define NTILE (LSEQ / 128)         // 16 tiles per dim
#define NROWS (BATCH * LSEQ)       // 32768

// ---------------------------------------------------------------------------
// K1: attn[b,i,j] = q[b,i,:].k[b,j,:]   128x128 tile/block, 8x8 microtile,
// K-chunk 16.  Fused per-tile softmax stats (row/col max + masked exp-sums).
// ---------------------------------------------------------------------------
__global__ __launch_bounds__(256) void k1_qk_stats(
    const float* __restrict__ q, const float* __restrict__ kmat,
    const float* __restrict__ mask, float* __restrict__ attn,
    float* __restrict__ rowMt, float* __restrict__ rowSt,
    float* __restrict__ colMt, float* __restrict__ colSt)
{
    const int b  = blockIdx.z;
    const int it = blockIdx.y * 128;
    const int jt = blockIdx.x * 128;
    const float* qb = q    + ((size_t)b * LSEQ + it) * DDIM;
    const float* kb = kmat + ((size_t)b * LSEQ + jt) * DDIM;

    __shared__ float As[16][132];          // transposed [k][row]
    __shared__ float Bs[16][132];
    __shared__ float rowMtile[128], rowStile[128], colMtile[128];
    __shared__ float colbuf[4][128];

    const int tid = threadIdx.x;
    const int r0 = (tid >> 4) << 2;   // 0..60 ; rows r0..r0+3 and +64
    const int c0 = (tid & 15) << 2;   // 0..60 ; cols c0..c0+3 and +64
    const int lr = tid >> 2;          // loader row 0..63 (and +64)
    const int lc = (tid & 3) << 2;    // loader k-col 0,4,8,12

    float acc[8][8];
#pragma unroll
    for (int u = 0; u < 8; ++u)
#pragma unroll
        for (int v = 0; v < 8; ++v) acc[u][v] = 0.f;

    float4 pa[2], pb[2];
#pragma unroll
    for (int p = 0; p < 2; ++p) {
        pa[p] = *(const float4*)(qb + (size_t)(lr + p * 64) * DDIM + lc);
        pb[p] = *(const float4*)(kb + (size_t)(lr + p * 64) * DDIM + lc);
    }

    for (int k0 = 0; k0 < DDIM; k0 += 16) {
#pragma unroll
        for (int p = 0; p < 2; ++p) {
            const int row = lr + p * 64;
            As[lc + 0][row] = pa[p].x; As[lc + 1][row] = pa[p].y;
            As[lc + 2][row] = pa[p].z; As[lc + 3][row] = pa[p].w;
            Bs[lc + 0][row] = pb[p].x; Bs[lc + 1][row] = pb[p].y;
            Bs[lc + 2][row] = pb[p].z; Bs[lc + 3][row] = pb[p].w;
        }
        if (k0 + 16 < DDIM) {
#pragma unroll
            for (int p = 0; p < 2; ++p) {
                pa[p] = *(const float4*)(qb + (size_t)(lr + p * 64) * DDIM + k0 + 16 + lc);
                pb[p] = *(const float4*)(kb + (size_t)(lr + p * 64) * DDIM + k0 + 16 + lc);
            }
        }
        __syncthreads();
#pragma unroll
        for (int kk = 0; kk < 16; ++kk) {
            float4 a0 = *(const float4*)&As[kk][r0];
            float4 a1 = *(const float4*)&As[kk][r0 + 64];
            float4 b0 = *(const float4*)&Bs[kk][c0];
            float4 b1 = *(const float4*)&Bs[kk][c0 + 64];
            float aa[8] = {a0.x, a0.y, a0.z, a0.w, a1.x, a1.y, a1.z, a1.w};
            float bb[8] = {b0.x, b0.y, b0.z, b0.w, b1.x, b1.y, b1.z, b1.w};
#pragma unroll
            for (int u = 0; u < 8; ++u)
#pragma unroll
                for (int v = 0; v < 8; ++v)
                    acc[u][v] = fmaf(aa[u], bb[v], acc[u][v]);
        }
        __syncthreads();
    }

    const int wave = tid >> 6;

    // ---- phase A: tile row/col maxes (unmasked) ----
#pragma unroll
    for (int u = 0; u < 8; ++u) {
        const int row = (u < 4) ? (r0 + u) : (64 + r0 + u - 4);
        float m = acc[u][0];
#pragma unroll
        for (int v = 1; v < 8; ++v) m = fmaxf(m, acc[u][v]);
        m = fmaxf(m, __shfl_xor(m, 1, 64));
        m = fmaxf(m, __shfl_xor(m, 2, 64));
        m = fmaxf(m, __shfl_xor(m, 4, 64));
        m = fmaxf(m, __shfl_xor(m, 8, 64));
        if ((tid & 15) == 0) rowMtile[row] = m;
    }
#pragma unroll
    for (int v = 0; v < 8; ++v) {
        const int col = (v < 4) ? (c0 + v) : (64 + c0 + v - 4);
        float m = acc[0][v];
#pragma unroll
        for (int u = 1; u < 8; ++u) m = fmaxf(m, acc[u][v]);
        m = fmaxf(m, __shfl_xor(m, 16, 64));
        m = fmaxf(m, __shfl_xor(m, 32, 64));
        if ((tid & 48) == 0) colbuf[wave][col] = m;
    }
    __syncthreads();
    if (tid < 128)
        colMtile[tid] = fmaxf(fmaxf(colbuf[0][tid], colbuf[1][tid]),
                              fmaxf(colbuf[2][tid], colbuf[3][tid]));
    __syncthreads();

    // ---- phase B: masked exp-sums + attn store ----
    float cs[8] = {0.f, 0.f, 0.f, 0.f, 0.f, 0.f, 0.f, 0.f};
    float mcv[8];
#pragma unroll
    for (int v = 0; v < 8; ++v)
        mcv[v] = colMtile[(v < 4) ? (c0 + v) : (64 + c0 + v - 4)];

    float* arow = attn + (((size_t)b * LSEQ + it) * LSEQ + jt);
#pragma unroll
    for (int u = 0; u < 8; ++u) {
        const int row = (u < 4) ? (r0 + u) : (64 + r0 + u - 4);
        const float* mrow = mask + ((size_t)(b * LSEQ + it + row)) * LSEQ + jt;
        float4 m0 = *(const float4*)(mrow + c0);
        float4 m1 = *(const float4*)(mrow + c0 + 64);
        *(float4*)(arow + (size_t)row * LSEQ + c0) =
            make_float4(acc[u][0], acc[u][1], acc[u][2], acc[u][3]);
        *(float4*)(arow + (size_t)row * LSEQ + c0 + 64) =
            make_float4(acc[u][4], acc[u][5], acc[u][6], acc[u][7]);
        const float mr = rowMtile[row];
        const float mm[8] = {m0.x, m0.y, m0.z, m0.w, m1.x, m1.y, m1.z, m1.w};
        float rs = 0.f;
#pragma unroll
        for (int v = 0; v < 8; ++v) {
            rs    += __expf(acc[u][v] - mr)     * mm[v];
            cs[v] += __expf(acc[u][v] - mcv[v]) * mm[v];
        }
        rs += __shfl_xor(rs, 1, 64);
        rs += __shfl_xor(rs, 2, 64);
        rs += __shfl_xor(rs, 4, 64);
        rs += __shfl_xor(rs, 8, 64);
        if ((tid & 15) == 0) rowStile[row] = rs;
    }
#pragma unroll
    for (int v = 0; v < 8; ++v) {
        const int col = (v < 4) ? (c0 + v) : (64 + c0 + v - 4);
        float s = cs[v];
        s += __shfl_xor(s, 16, 64);
        s += __shfl_xor(s, 32, 64);
        if ((tid & 48) == 0) colbuf[wave][col] = s;
    }
    __syncthreads();

    if (tid < 128) {
        const float colS = colbuf[0][tid] + colbuf[1][tid] +
                           colbuf[2][tid] + colbuf[3][tid];
        const size_t rIdx = (size_t)blockIdx.x * NROWS + b * LSEQ + it + tid;
        const size_t cIdx = (size_t)blockIdx.y * NROWS + b * LSEQ + jt + tid;
        rowMt[rIdx] = rowMtile[tid];
        rowSt[rIdx] = rowStile[tid];
        colMt[cIdx] = colMtile[tid];
        colSt[cIdx] = colS;
    }
}

// ---------------------------------------------------------------------------
// K2: combine per-tile stats -> global max & sum per row / col.
// ---------------------------------------------------------------------------
__global__ __launch_bounds__(256) void k2_combine(
    const float* __restrict__ rowMt, const float* __restrict__ rowSt,
    const float* __restrict__ colMt, const float* __restrict__ colSt,
    float* __restrict__ rmaxf, float* __restrict__ rsumf,
    float* __restrict__ cmaxf, float* __restrict__ csumf)
{
    const int id = blockIdx.x * 256 + threadIdx.x;   // [0, 2*NROWS)
    const bool isRow = (id < NROWS);
    const int off = isRow ? id : id - NROWS;
    const float* Mt = isRow ? rowMt : colMt;
    const float* St = isRow ? rowSt : colSt;

    float m = -INFINITY;
#pragma unroll
    for (int t = 0; t < NTILE; ++t) m = fmaxf(m, Mt[(size_t)t * NROWS + off]);
    float s = 0.f;
#pragma unroll
    for (int t = 0; t < NTILE; ++t)
        s += St[(size_t)t * NROWS + off] * __expf(Mt[(size_t)t * NROWS + off] - m);

    if (isRow) { rmaxf[off] = m; rsumf[off] = s; }
    else       { cmaxf[off] = m; csumf[off] = s; }
}

// ---------------------------------------------------------------------------
// K3: gated = mask*exp(2x - m_row - m_col)*isr*isc (in place over attn),
// fused with out = gated @ v.  128 threads, 32-row tile, 4x8 microtile.
// A-frag LDS reads are wave-broadcast (4 distinct addrs) -> low LDS-pipe cost.
// ---------------------------------------------------------------------------
__global__ __launch_bounds__(128) void k3_gated_out(
    const float* __restrict__ mask, const float* __restrict__ v,
    const float* __restrict__ rmaxf, const float* __restrict__ cmaxf,
    const float* __restrict__ rsumf, const float* __restrict__ csumf,
    float* __restrict__ gated, float* __restrict__ outp)
{
    const int b   = blockIdx.y;
    const int it0 = blockIdx.x * 32;

    __shared__ float Gs[32][36];     // gated chunk, transposed [j][i]
    __shared__ float Vs[32][128];    // v chunk [j][dv]
    __shared__ float RowM[32], RowIS[32];
    __shared__ float ColM[32], ColIS[32];

    const int tid = threadIdx.x;
    if (tid < 32) {
        RowM[tid]  = rmaxf[b * LSEQ + it0 + tid];
        RowIS[tid] = 1.f / (rsumf[b * LSEQ + it0 + tid] + EPSV);
    }

    const int r0  = (tid >> 4) << 2;  // 0..28 : out rows
    const int c0  = (tid & 15) << 2;  // 0..60 : out cols (and +64)
    const int gr  = tid >> 3;         // 0..15 : gated rows gr, gr+16
    const int gc4 = (tid & 7) << 2;   // 0..28 : gated col-in-chunk
    const int vr  = tid >> 5;         // 0..3  : v loader row (+4p)
    const int vc  = (tid & 31) << 2;  // 0..124: v loader col

    float acc[4][8];
#pragma unroll
    for (int u = 0; u < 4; ++u)
#pragma unroll
        for (int w = 0; w < 8; ++w) acc[u][w] = 0.f;

    const float* mb = mask  + ((size_t)b * LSEQ + it0) * LSEQ;
    float*       gb = gated + ((size_t)b * LSEQ + it0) * LSEQ;
    const float* vb = v + (size_t)b * LSEQ * DDIM;

    float4 xpre[2], mpre[2];
#pragma unroll
    for (int p = 0; p < 2; ++p) {
        const int row = gr + p * 16;
        xpre[p] = *(const float4*)(gb + (size_t)row * LSEQ + gc4);
        mpre[p] = *(const float4*)(mb + (size_t)row * LSEQ + gc4);
    }

    for (int j0 = 0; j0 < LSEQ; j0 += 32) {
        __syncthreads();   // previous chunk fully consumed
        if (tid < 32) {
            ColM[tid]  = cmaxf[b * LSEQ + j0 + tid];
            ColIS[tid] = 1.f / (csumf[b * LSEQ + j0 + tid] + EPSV);
        }
#pragma unroll
        for (int p = 0; p < 8; ++p) {
            const int row = vr + p * 4;
            *(float4*)&Vs[row][vc] = *(const float4*)(vb + (size_t)(j0 + row) * DDIM + vc);
        }
        __syncthreads();   // ColM/ColIS + Vs visible

        float4 xc[2] = {xpre[0], xpre[1]};
        float4 mk[2] = {mpre[0], mpre[1]};
        if (j0 + 32 < LSEQ) {
#pragma unroll
            for (int p = 0; p < 2; ++p) {
                const int row = gr + p * 16;
                xpre[p] = *(const float4*)(gb + (size_t)row * LSEQ + j0 + 32 + gc4);
                mpre[p] = *(const float4*)(mb + (size_t)row * LSEQ + j0 + 32 + gc4);
            }
        }
#pragma unroll
        for (int p = 0; p < 2; ++p) {
            const int row = gr + p * 16;
            const float mrw = RowM[row], isr = RowIS[row];
            float g0 = mk[p].x * __expf(2.f * xc[p].x - mrw - ColM[gc4 + 0]) * isr * ColIS[gc4 + 0];
            float g1 = mk[p].y * __expf(2.f * xc[p].y - mrw - ColM[gc4 + 1]) * isr * ColIS[gc4 + 1];
            float g2 = mk[p].z * __expf(2.f * xc[p].z - mrw - ColM[gc4 + 2]) * isr * ColIS[gc4 + 2];
            float g3 = mk[p].w * __expf(2.f * xc[p].w - mrw - ColM[gc4 + 3]) * isr * ColIS[gc4 + 3];
            *(float4*)(gb + (size_t)row * LSEQ + j0 + gc4) = make_float4(g0, g1, g2, g3);
            Gs[gc4 + 0][row] = g0; Gs[gc4 + 1][row] = g1;
            Gs[gc4 + 2][row] = g2; Gs[gc4 + 3][row] = g3;
        }
        __syncthreads();   // Gs ready
#pragma unroll
        for (int kk = 0; kk < 32; ++kk) {
            float4 a4 = *(const float4*)&Gs[kk][r0];
            float4 b0 = *(const float4*)&Vs[kk][c0];
            float4 b1 = *(const float4*)&Vs[kk][c0 + 64];
            float av[4] = {a4.x, a4.y, a4.z, a4.w};
            float bv[8] = {b0.x, b0.y, b0.z, b0.w, b1.x, b1.y, b1.z, b1.w};
#pragma unroll
            for (int u = 0; u < 4; ++u)
#pragma unroll
                for (int w = 0; w < 8; ++w)
                    acc[u][w] = fmaf(av[u], bv[w], acc[u][w]);
        }
    }

    float* ob = outp + ((size_t)b * LSEQ + it0) * DDIM;
#pragma unroll
    for (int u = 0; u < 4; ++u) {
        *(float4*)(ob + (size_t)(r0 + u) * DDIM + c0) =
            make_float4(acc[u][0], acc[u][1], acc[u][2], acc[u][3]);
        *(float4*)(ob + (size_t)(r0 + u) * DDIM + c0 + 64) =
            make_float4(acc[u][4], acc[u][5], acc[u][6], acc[u][7]);
    }
}

// ---------------------------------------------------------------------------
extern "C" void kernel_launch(void* const* d_in, const int* in_sizes, int n_in,
                              void* d_out, int out_size, void* d_ws, size_t ws_size,
                              hipStream_t stream)
{
    (void)in_sizes; (void)n_in; (void)out_size; (void)ws_size;
    const float* q    = (const float*)d_in[0];
    const float* k    = (const float*)d_in[1];
    const float* v    = (const float*)d_in[2];
    const float* mask = (const float*)d_in[3];

    float* outp  = (float*)d_out;                                   // B*L*D
    float* gated = (float*)d_out + (size_t)BATCH * LSEQ * DDIM;     // B*L*L

    float* rowMt = (float*)d_ws;                 // [NTILE][NROWS]
    float* rowSt = rowMt + (size_t)NTILE * NROWS;
    float* colMt = rowSt + (size_t)NTILE * NROWS;
    float* colSt = colMt + (size_t)NTILE * NROWS;
    float* rmaxf = colSt + (size_t)NTILE * NROWS;
    float* rsumf = rmaxf + NROWS;
    float* cmaxf = rsumf + NROWS;
    float* csumf = cmaxf + NROWS;

    dim3 g1(LSEQ / 128, LSEQ / 128, BATCH);
    k1_qk_stats<<<g1, dim3(256), 0, stream>>>(q, k, mask, gated,
                                              rowMt, rowSt, colMt, colSt);

    k2_combine<<<dim3(2 * NROWS / 256), dim3(256), 0, stream>>>(
        rowMt, rowSt, colMt, colSt, rmaxf, rsumf, cmaxf, csumf);

    dim3 g3(LSEQ / 32, BATCH);
    k3_gated_out<<<g3, dim3(128), 0, stream>>>(mask, v, rmaxf, cmaxf,
                                               rsumf, csumf, gated, outp);
}